// Round 1
// baseline (232.040 us; speedup 1.0000x reference)
//
#include <hip/hip_runtime.h>

typedef __attribute__((ext_vector_type(8))) short short8_t;
typedef __attribute__((ext_vector_type(4))) float float4_t;

#define MFMA16(a, b, c) __builtin_amdgcn_mfma_f32_16x16x32_bf16((a), (b), (c), 0, 0, 0)

// fp32 -> bf16 round-to-nearest-even (finite inputs only)
static __device__ __forceinline__ unsigned short f2b(float f) {
  unsigned int x = __builtin_bit_cast(unsigned int, f);
  x = (x + 0x7fffu + ((x >> 16) & 1u)) >> 16;
  return (unsigned short)x;
}

// ---------------------------------------------------------------------------
// Kernel 1: MT[j][d] = (1/32) * sum_k binding[j][k] * Wq[d][k]   (bf16 out)
// grid (8 j-tiles, 8 d-tiles), block 256 (4 waves). Tile 64j x 128d, BK=64.
// ---------------------------------------------------------------------------
__global__ __launch_bounds__(256, 2) void mt_kernel(
    const float* __restrict__ Wq, const float* __restrict__ binding,
    short* __restrict__ MT) {
  __shared__ short bl[64 * 64];
  __shared__ short wl[128 * 64];
  const int tid = threadIdx.x;
  const int wid = tid >> 6;
  const int lane = tid & 63;
  const int ml = lane & 15;
  const int g = lane >> 4;
  const int klane = g * 8;
  const int j0 = blockIdx.x * 64;
  const int d0 = blockIdx.y * 128;

  float4_t acc[4][2];
#pragma unroll
  for (int a = 0; a < 4; ++a)
#pragma unroll
    for (int b = 0; b < 2; ++b) acc[a][b] = (float4_t)(0.0f);

  const int sr = tid >> 3;
  const int sc = (tid & 7) << 3;

  for (int kc = 0; kc < 1024; kc += 64) {
#pragma unroll
    for (int rr = sr; rr < 64; rr += 32) {
      const float* s = binding + (size_t)(j0 + rr) * 1024 + kc + sc;
      float4 f0 = *(const float4*)s;
      float4 f1 = *(const float4*)(s + 4);
      short8_t v;
      v[0] = (short)f2b(f0.x); v[1] = (short)f2b(f0.y);
      v[2] = (short)f2b(f0.z); v[3] = (short)f2b(f0.w);
      v[4] = (short)f2b(f1.x); v[5] = (short)f2b(f1.y);
      v[6] = (short)f2b(f1.z); v[7] = (short)f2b(f1.w);
      *(short8_t*)((char*)bl + ((((rr * 64 + sc) * 2) ^ ((rr & 7) << 4)))) = v;
    }
#pragma unroll
    for (int rr = sr; rr < 128; rr += 32) {
      const float* s = Wq + (size_t)(d0 + rr) * 1024 + kc + sc;
      float4 f0 = *(const float4*)s;
      float4 f1 = *(const float4*)(s + 4);
      short8_t v;
      v[0] = (short)f2b(f0.x); v[1] = (short)f2b(f0.y);
      v[2] = (short)f2b(f0.z); v[3] = (short)f2b(f0.w);
      v[4] = (short)f2b(f1.x); v[5] = (short)f2b(f1.y);
      v[6] = (short)f2b(f1.z); v[7] = (short)f2b(f1.w);
      *(short8_t*)((char*)wl + ((((rr * 64 + sc) * 2) ^ ((rr & 7) << 4)))) = v;
    }
    __syncthreads();
#pragma unroll
    for (int ks = 0; ks < 2; ++ks) {
      const int col = ks * 32 + klane;
      short8_t af[4], bfr[2];
#pragma unroll
      for (int mr = 0; mr < 4; ++mr) {
        int row = mr * 16 + ml;
        af[mr] = *(const short8_t*)((const char*)bl +
                                    (((row * 64 + col) * 2) ^ ((row & 7) << 4)));
      }
#pragma unroll
      for (int nr = 0; nr < 2; ++nr) {
        int row = wid * 32 + nr * 16 + ml;
        bfr[nr] = *(const short8_t*)((const char*)wl +
                                     (((row * 64 + col) * 2) ^ ((row & 7) << 4)));
      }
#pragma unroll
      for (int mr = 0; mr < 4; ++mr)
#pragma unroll
        for (int nr = 0; nr < 2; ++nr)
          acc[mr][nr] = MFMA16(af[mr], bfr[nr], acc[mr][nr]);
    }
    __syncthreads();
  }
#pragma unroll
  for (int mr = 0; mr < 4; ++mr)
#pragma unroll
    for (int nr = 0; nr < 2; ++nr)
#pragma unroll
      for (int i = 0; i < 4; ++i) {
        int j = j0 + mr * 16 + g * 4 + i;
        int d = d0 + wid * 32 + nr * 16 + ml;
        MT[(size_t)j * 1024 + d] = (short)f2b(acc[mr][nr][i] * 0.03125f);
      }
}

// ---------------------------------------------------------------------------
// Kernel 2: symT[k][j] = bf16(symbols[j][k])  (transpose 512x1024 -> 1024x512)
// grid (16 k-tiles, 8 j-tiles), block 256. 64x64 tiles via LDS.
// ---------------------------------------------------------------------------
__global__ __launch_bounds__(256) void tr_kernel(const float* __restrict__ sym,
                                                 short* __restrict__ symT) {
  __shared__ short t[64][65];
  const int tid = threadIdx.x;
  const int k0 = blockIdx.x * 64;
  const int j0 = blockIdx.y * 64;
  const int sr = tid >> 3;
  const int sc = (tid & 7) << 3;
#pragma unroll
  for (int rr = sr; rr < 64; rr += 32) {
    const float* s = sym + (size_t)(j0 + rr) * 1024 + k0 + sc;
    float4 f0 = *(const float4*)s;
    float4 f1 = *(const float4*)(s + 4);
    t[rr][sc + 0] = (short)f2b(f0.x); t[rr][sc + 1] = (short)f2b(f0.y);
    t[rr][sc + 2] = (short)f2b(f0.z); t[rr][sc + 3] = (short)f2b(f0.w);
    t[rr][sc + 4] = (short)f2b(f1.x); t[rr][sc + 5] = (short)f2b(f1.y);
    t[rr][sc + 6] = (short)f2b(f1.z); t[rr][sc + 7] = (short)f2b(f1.w);
  }
  __syncthreads();
  const int kk = tid >> 4;
  const int jj = (tid & 15) << 2;
#pragma unroll
  for (int k = kk; k < 64; k += 16) {
    short* dst = symT + (size_t)(k0 + k) * 512 + j0 + jj;
    dst[0] = t[jj + 0][k];
    dst[1] = t[jj + 1][k];
    dst[2] = t[jj + 2][k];
    dst[3] = t[jj + 3][k];
  }
}

// ---------------------------------------------------------------------------
// Kernel 3: fused  logits = bf16(inp) @ MT^T ; softmax ; out = P @ symT^T
// grid 512 (64-row tiles), block 512 (8 waves).
// Phase 1: each wave owns a 64-col j-strip (N_rep=4), A staged in LDS.
// Phase 2: each wave owns a 128-col d-strip (N_rep=8), P from LDS.
// ---------------------------------------------------------------------------
__global__ __launch_bounds__(512, 2) void fused_kernel(
    const float* __restrict__ inp, const short* __restrict__ MT,
    const short* __restrict__ symT, float* __restrict__ out) {
  __shared__ short A_lds[64 * 64];
  __shared__ short P_lds[64 * 512];
  __shared__ float red1[512];
  __shared__ float red2[512];
  __shared__ float rowinv[64];

  const int tid = threadIdx.x;
  const int wid = tid >> 6;
  const int lane = tid & 63;
  const int ml = lane & 15;
  const int g = lane >> 4;
  const int klane = g * 8;
  const size_t row0 = (size_t)blockIdx.x * 64;

  float4_t acc[4][4];
#pragma unroll
  for (int a = 0; a < 4; ++a)
#pragma unroll
    for (int b = 0; b < 4; ++b) acc[a][b] = (float4_t)(0.0f);

  const int sr = tid >> 3;        // 0..63
  const int sc = (tid & 7) << 3;  // 0..56

  // ---- Phase 1: logits ----
  for (int kc = 0; kc < 1024; kc += 64) {
    const float* src = inp + (row0 + sr) * 1024 + kc + sc;
    float4 f0 = *(const float4*)src;
    float4 f1 = *(const float4*)(src + 4);
    short8_t v;
    v[0] = (short)f2b(f0.x); v[1] = (short)f2b(f0.y);
    v[2] = (short)f2b(f0.z); v[3] = (short)f2b(f0.w);
    v[4] = (short)f2b(f1.x); v[5] = (short)f2b(f1.y);
    v[6] = (short)f2b(f1.z); v[7] = (short)f2b(f1.w);
    *(short8_t*)((char*)A_lds + ((((sr * 64 + sc) * 2) ^ ((sr & 7) << 4)))) = v;
    __syncthreads();
#pragma unroll
    for (int ks = 0; ks < 2; ++ks) {
      const int col = ks * 32 + klane;
      short8_t af[4], bfr[4];
#pragma unroll
      for (int mr = 0; mr < 4; ++mr) {
        int row = mr * 16 + ml;
        af[mr] = *(const short8_t*)((const char*)A_lds +
                                    (((row * 64 + col) * 2) ^ ((row & 7) << 4)));
      }
#pragma unroll
      for (int nr = 0; nr < 4; ++nr)
        bfr[nr] = *(const short8_t*)(MT +
                                     (size_t)(wid * 64 + nr * 16 + ml) * 1024 +
                                     kc + col);
#pragma unroll
      for (int mr = 0; mr < 4; ++mr)
#pragma unroll
        for (int nr = 0; nr < 4; ++nr)
          acc[mr][nr] = MFMA16(af[mr], bfr[nr], acc[mr][nr]);
    }
    __syncthreads();
  }

  // ---- Softmax (rows distributed: row = mr*16 + g*4 + i, cols = wid-strip) ----
#pragma unroll
  for (int mr = 0; mr < 4; ++mr)
#pragma unroll
    for (int i = 0; i < 4; ++i) {
      float v = fmaxf(fmaxf(acc[mr][0][i], acc[mr][1][i]),
                      fmaxf(acc[mr][2][i], acc[mr][3][i]));
      v = fmaxf(v, __shfl_xor(v, 1));
      v = fmaxf(v, __shfl_xor(v, 2));
      v = fmaxf(v, __shfl_xor(v, 4));
      v = fmaxf(v, __shfl_xor(v, 8));
      if (ml == 0) red1[wid * 64 + mr * 16 + g * 4 + i] = v;
    }
  __syncthreads();
#pragma unroll
  for (int mr = 0; mr < 4; ++mr)
#pragma unroll
    for (int i = 0; i < 4; ++i) {
      const int row = mr * 16 + g * 4 + i;
      float m = red1[row];
#pragma unroll
      for (int w = 1; w < 8; ++w) m = fmaxf(m, red1[w * 64 + row]);
      float ps = 0.0f;
#pragma unroll
      for (int nr = 0; nr < 4; ++nr) {
        float p = __expf(acc[mr][nr][i] - m);
        ps += p;
        int col = wid * 64 + nr * 16 + ml;
        int byte = ((row * 512 + col) * 2) ^ ((row & 7) << 4);
        *(short*)((char*)P_lds + byte) = (short)f2b(p);
      }
      ps += __shfl_xor(ps, 1);
      ps += __shfl_xor(ps, 2);
      ps += __shfl_xor(ps, 4);
      ps += __shfl_xor(ps, 8);
      if (ml == 0) red2[wid * 64 + row] = ps;
    }
  __syncthreads();
  if (tid < 64) {
    float s = 0.0f;
#pragma unroll
    for (int w = 0; w < 8; ++w) s += red2[w * 64 + tid];
    rowinv[tid] = 1.0f / s;
  }
  __syncthreads();

  // ---- Phase 2: out = P @ symT^T ----
  float4_t acc2[4][8];
#pragma unroll
  for (int a = 0; a < 4; ++a)
#pragma unroll
    for (int b = 0; b < 8; ++b) acc2[a][b] = (float4_t)(0.0f);

  for (int kc = 0; kc < 512; kc += 32) {
    const int col = kc + klane;
    short8_t af[4];
#pragma unroll
    for (int mr = 0; mr < 4; ++mr) {
      int row = mr * 16 + ml;
      af[mr] = *(const short8_t*)((const char*)P_lds +
                                  (((row * 512 + col) * 2) ^ ((row & 7) << 4)));
    }
    short8_t bfr[8];
#pragma unroll
    for (int nr = 0; nr < 8; ++nr)
      bfr[nr] = *(const short8_t*)(symT +
                                   (size_t)(wid * 128 + nr * 16 + ml) * 512 +
                                   col);
#pragma unroll
    for (int mr = 0; mr < 4; ++mr)
#pragma unroll
      for (int nr = 0; nr < 8; ++nr)
        acc2[mr][nr] = MFMA16(af[mr], bfr[nr], acc2[mr][nr]);
  }

  // ---- Epilogue: scale by 1/rowsum, store fp32 ----
#pragma unroll
  for (int mr = 0; mr < 4; ++mr) {
    float rv[4];
#pragma unroll
    for (int i = 0; i < 4; ++i) rv[i] = rowinv[mr * 16 + g * 4 + i];
#pragma unroll
    for (int nr = 0; nr < 8; ++nr)
#pragma unroll
      for (int i = 0; i < 4; ++i) {
        size_t o = (row0 + mr * 16 + g * 4 + i) * 1024 + wid * 128 + nr * 16 + ml;
        out[o] = acc2[mr][nr][i] * rv[i];
      }
  }
}

extern "C" void kernel_launch(void* const* d_in, const int* in_sizes, int n_in,
                              void* d_out, int out_size, void* d_ws,
                              size_t ws_size, hipStream_t stream) {
  const float* inp = (const float*)d_in[0];      // [8,4096,1024]
  const float* Wq = (const float*)d_in[1];       // [1024,1024]
  const float* binding = (const float*)d_in[2];  // [512,1024]
  const float* symbols = (const float*)d_in[3];  // [512,1024]
  float* out = (float*)d_out;                    // [8,4096,1024]

  short* MT = (short*)d_ws;             // [512][1024] bf16 (includes 1/32 scale)
  short* symT = MT + 512 * 1024;        // [1024][512] bf16

  mt_kernel<<<dim3(8, 8), 256, 0, stream>>>(Wq, binding, MT);
  tr_kernel<<<dim3(16, 8), 256, 0, stream>>>(symbols, symT);
  fused_kernel<<<512, 512, 0, stream>>>(inp, MT, symT, out);
}

// Round 4
// 213.908 us; speedup vs baseline: 1.0848x; 1.0848x over previous
//
#include <hip/hip_runtime.h>

typedef __attribute__((ext_vector_type(8))) short short8_t;
typedef __attribute__((ext_vector_type(4))) short short4_t;
typedef __attribute__((ext_vector_type(4))) float float4_t;

#define MFMA16(a, b, c) __builtin_amdgcn_mfma_f32_16x16x32_bf16((a), (b), (c), 0, 0, 0)
#define GLOAD_LDS16(g, l)                                                   \
  __builtin_amdgcn_global_load_lds(                                         \
      (const __attribute__((address_space(1))) void*)(g),                   \
      (__attribute__((address_space(3))) void*)(l), 16, 0, 0)

// fp32 -> bf16 round-to-nearest-even (finite inputs only)
static __device__ __forceinline__ unsigned short f2b(float f) {
  unsigned int x = __builtin_bit_cast(unsigned int, f);
  x = (x + 0x7fffu + ((x >> 16) & 1u)) >> 16;
  return (unsigned short)x;
}

// ---------------------------------------------------------------------------
// Kernel 1: MT[j][d] = (1/32) * sum_k binding[j][k] * Wq[d][k]   (bf16 out)
// grid (8 j-tiles, 8 d-tiles), block 256 (4 waves). Tile 64j x 128d, BK=64.
// ---------------------------------------------------------------------------
__global__ __launch_bounds__(256, 2) void mt_kernel(
    const float* __restrict__ Wq, const float* __restrict__ binding,
    short* __restrict__ MT) {
  __shared__ short bl[64 * 64];
  __shared__ short wl[128 * 64];
  const int tid = threadIdx.x;
  const int wid = tid >> 6;
  const int lane = tid & 63;
  const int ml = lane & 15;
  const int g = lane >> 4;
  const int klane = g * 8;
  const int j0 = blockIdx.x * 64;
  const int d0 = blockIdx.y * 128;

  float4_t acc[4][2];
#pragma unroll
  for (int a = 0; a < 4; ++a)
#pragma unroll
    for (int b = 0; b < 2; ++b) acc[a][b] = (float4_t)(0.0f);

  const int sr = tid >> 3;
  const int sc = (tid & 7) << 3;

  for (int kc = 0; kc < 1024; kc += 64) {
#pragma unroll
    for (int rr = sr; rr < 64; rr += 32) {
      const float* s = binding + (size_t)(j0 + rr) * 1024 + kc + sc;
      float4 f0 = *(const float4*)s;
      float4 f1 = *(const float4*)(s + 4);
      short8_t v;
      v[0] = (short)f2b(f0.x); v[1] = (short)f2b(f0.y);
      v[2] = (short)f2b(f0.z); v[3] = (short)f2b(f0.w);
      v[4] = (short)f2b(f1.x); v[5] = (short)f2b(f1.y);
      v[6] = (short)f2b(f1.z); v[7] = (short)f2b(f1.w);
      *(short8_t*)((char*)bl + ((((rr * 64 + sc) * 2) ^ ((rr & 7) << 4)))) = v;
    }
#pragma unroll
    for (int rr = sr; rr < 128; rr += 32) {
      const float* s = Wq + (size_t)(d0 + rr) * 1024 + kc + sc;
      float4 f0 = *(const float4*)s;
      float4 f1 = *(const float4*)(s + 4);
      short8_t v;
      v[0] = (short)f2b(f0.x); v[1] = (short)f2b(f0.y);
      v[2] = (short)f2b(f0.z); v[3] = (short)f2b(f0.w);
      v[4] = (short)f2b(f1.x); v[5] = (short)f2b(f1.y);
      v[6] = (short)f2b(f1.z); v[7] = (short)f2b(f1.w);
      *(short8_t*)((char*)wl + ((((rr * 64 + sc) * 2) ^ ((rr & 7) << 4)))) = v;
    }
    __syncthreads();
#pragma unroll
    for (int ks = 0; ks < 2; ++ks) {
      const int col = ks * 32 + klane;
      short8_t af[4], bfr[2];
#pragma unroll
      for (int mr = 0; mr < 4; ++mr) {
        int row = mr * 16 + ml;
        af[mr] = *(const short8_t*)((const char*)bl +
                                    (((row * 64 + col) * 2) ^ ((row & 7) << 4)));
      }
#pragma unroll
      for (int nr = 0; nr < 2; ++nr) {
        int row = wid * 32 + nr * 16 + ml;
        bfr[nr] = *(const short8_t*)((const char*)wl +
                                     (((row * 64 + col) * 2) ^ ((row & 7) << 4)));
      }
#pragma unroll
      for (int mr = 0; mr < 4; ++mr)
#pragma unroll
        for (int nr = 0; nr < 2; ++nr)
          acc[mr][nr] = MFMA16(af[mr], bfr[nr], acc[mr][nr]);
    }
    __syncthreads();
  }
#pragma unroll
  for (int mr = 0; mr < 4; ++mr)
#pragma unroll
    for (int nr = 0; nr < 2; ++nr)
#pragma unroll
      for (int i = 0; i < 4; ++i) {
        int j = j0 + mr * 16 + g * 4 + i;
        int d = d0 + wid * 32 + nr * 16 + ml;
        MT[(size_t)j * 1024 + d] = (short)f2b(acc[mr][nr][i] * 0.03125f);
      }
}

// ---------------------------------------------------------------------------
// Kernel 2: symT[k][j] = bf16(symbols[j][k])  (transpose 512x1024 -> 1024x512)
// ---------------------------------------------------------------------------
__global__ __launch_bounds__(256) void tr_kernel(const float* __restrict__ sym,
                                                 short* __restrict__ symT) {
  __shared__ short t[64][65];
  const int tid = threadIdx.x;
  const int k0 = blockIdx.x * 64;
  const int j0 = blockIdx.y * 64;
  const int sr = tid >> 3;
  const int sc = (tid & 7) << 3;
#pragma unroll
  for (int rr = sr; rr < 64; rr += 32) {
    const float* s = sym + (size_t)(j0 + rr) * 1024 + k0 + sc;
    float4 f0 = *(const float4*)s;
    float4 f1 = *(const float4*)(s + 4);
    t[rr][sc + 0] = (short)f2b(f0.x); t[rr][sc + 1] = (short)f2b(f0.y);
    t[rr][sc + 2] = (short)f2b(f0.z); t[rr][sc + 3] = (short)f2b(f0.w);
    t[rr][sc + 4] = (short)f2b(f1.x); t[rr][sc + 5] = (short)f2b(f1.y);
    t[rr][sc + 6] = (short)f2b(f1.z); t[rr][sc + 7] = (short)f2b(f1.w);
  }
  __syncthreads();
  const int kk = tid >> 4;
  const int jj = (tid & 15) << 2;
#pragma unroll
  for (int k = kk; k < 64; k += 16) {
    short* dst = symT + (size_t)(k0 + k) * 512 + j0 + jj;
    dst[0] = t[jj + 0][k];
    dst[1] = t[jj + 1][k];
    dst[2] = t[jj + 2][k];
    dst[3] = t[jj + 3][k];
  }
}

// ---------------------------------------------------------------------------
// Kernel 3: score. logitsT = MT @ bf16(inp)^T (swapped operands), row max,
// P = bf16(exp(x - m)) UNNORMALIZED -> global ws, rowinv = 1/rowsum (fp32).
// grid 512 (64-row tiles), block 512 (8 waves), wave owns a 64-j strip.
// Raw barrier + sched_barrier(0) so ds_reads cannot hoist above s_barrier
// (llvm.amdgcn.s.barrier is NOT a memory fence — the R2/R3 race).
// ---------------------------------------------------------------------------
__global__ __launch_bounds__(512, 2) void score_kernel(
    const float* __restrict__ inp, const short* __restrict__ MT,
    short* __restrict__ P, float* __restrict__ rowinv) {
  __shared__ short Abuf[2][64 * 64];
  __shared__ float redmax[8 * 64];
  __shared__ float redsum[8 * 64];

  const int tid = threadIdx.x;
  const int wid = tid >> 6;
  const int lane = tid & 63;
  const int ml = lane & 15;
  const int g = lane >> 4;
  const size_t row0 = (size_t)blockIdx.x * 64;

  float4_t acc[4][4];  // acc[jm][rm]: D[j][r], j = wid*64+jm*16+g*4+i, r = rm*16+ml
#pragma unroll
  for (int a = 0; a < 4; ++a)
#pragma unroll
    for (int b = 0; b < 4; ++b) acc[a][b] = (float4_t)(0.0f);

  const int sr = tid >> 3;        // 0..63 row within tile
  const int sc = (tid & 7) << 3;  // col chunk
  const float* srcbase = inp + (row0 + sr) * 1024 + sc;

  float4 f0 = *(const float4*)(srcbase);
  float4 f1 = *(const float4*)(srcbase + 4);

  for (int kt = 0; kt < 16; ++kt) {
    // convert prefetched fp32 -> bf16, write to current LDS buffer (swizzled)
    short8_t v;
    v[0] = (short)f2b(f0.x); v[1] = (short)f2b(f0.y);
    v[2] = (short)f2b(f0.z); v[3] = (short)f2b(f0.w);
    v[4] = (short)f2b(f1.x); v[5] = (short)f2b(f1.y);
    v[6] = (short)f2b(f1.z); v[7] = (short)f2b(f1.w);
    *(short8_t*)((char*)Abuf[kt & 1] + (((sr * 64 + sc) * 2) ^ ((sr & 7) << 4))) = v;
    // issue next tile's global loads (consumed at next iteration's convert)
    if (kt < 15) {
      const float* s2 = srcbase + (kt + 1) * 64;
      f0 = *(const float4*)s2;
      f1 = *(const float4*)(s2 + 4);
    }
    // drain own LDS write; global prefetch stays in flight
    asm volatile("s_waitcnt lgkmcnt(0)" ::: "memory");
    __builtin_amdgcn_s_barrier();
    // pin: nothing (esp. the ds_reads below) may be scheduled above the barrier
    __builtin_amdgcn_sched_barrier(0);

    const char* bb = (const char*)Abuf[kt & 1];
    const short* mtb = MT + (size_t)(wid * 64 + ml) * 1024 + kt * 64;
#pragma unroll
    for (int ks = 0; ks < 2; ++ks) {
      const int col = ks * 32 + g * 8;
      short8_t af[4], bfr[4];
#pragma unroll
      for (int jm = 0; jm < 4; ++jm)
        af[jm] = *(const short8_t*)(mtb + jm * 16 * 1024 + col);
#pragma unroll
      for (int rm = 0; rm < 4; ++rm) {
        int row = rm * 16 + ml;
        bfr[rm] = *(const short8_t*)(bb + (((row * 64 + col) * 2) ^ ((row & 7) << 4)));
      }
#pragma unroll
      for (int jm = 0; jm < 4; ++jm)
#pragma unroll
        for (int rm = 0; rm < 4; ++rm)
          acc[jm][rm] = MFMA16(af[jm], bfr[rm], acc[jm][rm]);
    }
    // no trailing barrier: next write targets the other buffer, and the
    // kt+1 barrier (all waves' lgkm drained) orders reuse of this buffer.
  }

  // ---- row max over j (512), rows r = rm*16+ml ----
#pragma unroll
  for (int rm = 0; rm < 4; ++rm) {
    float mx = -1e30f;
#pragma unroll
    for (int jm = 0; jm < 4; ++jm)
#pragma unroll
      for (int i = 0; i < 4; ++i) mx = fmaxf(mx, acc[jm][rm][i]);
    mx = fmaxf(mx, __shfl_xor(mx, 16));
    mx = fmaxf(mx, __shfl_xor(mx, 32));
    if (g == 0) redmax[wid * 64 + rm * 16 + ml] = mx;
  }
  __syncthreads();

  // ---- exp(x-m), write unnormalized bf16 P, reduce row sums ----
#pragma unroll
  for (int rm = 0; rm < 4; ++rm) {
    const int row = rm * 16 + ml;
    float m = redmax[row];
#pragma unroll
    for (int w = 1; w < 8; ++w) m = fmaxf(m, redmax[w * 64 + row]);
    float s = 0.0f;
#pragma unroll
    for (int jm = 0; jm < 4; ++jm) {
      short4_t pv;
#pragma unroll
      for (int i = 0; i < 4; ++i) {
        float p = __expf(acc[jm][rm][i] - m);
        s += p;
        pv[i] = (short)f2b(p);
      }
      *(short4_t*)(P + ((row0 + row) << 9) + wid * 64 + jm * 16 + g * 4) = pv;
    }
    s += __shfl_xor(s, 16);
    s += __shfl_xor(s, 32);
    if (g == 0) redsum[wid * 64 + row] = s;
  }
  __syncthreads();

  // ---- wave 0 writes 1/rowsum ----
  if (wid == 0 && g == 0) {
#pragma unroll
    for (int rm = 0; rm < 4; ++rm) {
      const int row = rm * 16 + ml;
      float t = 0.0f;
#pragma unroll
      for (int w = 0; w < 8; ++w) t += redsum[w * 64 + row];
      rowinv[row0 + row] = 1.0f / t;
    }
  }
}

// ---------------------------------------------------------------------------
// Kernel 4: out[r][d] = rowinv[r] * sum_j P[r][j] * symT[d][j].  128x128 tile,
// BK=64, 256 threads (4 waves, 2x2), global_load_lds double-buffered prefetch,
// XCD-bijective block swizzle (2048 blocks % 8 == 0).
// ---------------------------------------------------------------------------
__global__ __launch_bounds__(256, 2) void pv_kernel(
    const short* __restrict__ P, const short* __restrict__ symT,
    const float* __restrict__ rowinv, float* __restrict__ out) {
  __shared__ short Abuf[2][128 * 64];
  __shared__ short Bbuf[2][128 * 64];
  const int tid = threadIdx.x;
  const int lane = tid & 63;
  const int ml = lane & 15;
  const int g = lane >> 4;
  const int wid = tid >> 6;
  const int wr = wid >> 1;
  const int wc = wid & 1;

  const int b = blockIdx.x;
  const int swz = (b & 7) * 256 + (b >> 3);
  const size_t m0 = (size_t)(swz >> 3) * 128;
  const int n0 = (swz & 7) * 128;

  float4_t acc[4][4];
#pragma unroll
  for (int a = 0; a < 4; ++a)
#pragma unroll
    for (int c = 0; c < 4; ++c) acc[a][c] = (float4_t)(0.0f);

#define STAGE(t, buf)                                                        \
  {                                                                          \
    const int kc_ = (t) * 64;                                                \
    _Pragma("unroll")                                                        \
    for (int i_ = 0; i_ < 4; ++i_) {                                         \
      const int c_ = tid + i_ * 256;                                         \
      GLOAD_LDS16(P + (m0 + (c_ >> 3)) * 512 + kc_ + ((c_ & 7) << 3),        \
                  (char*)Abuf[buf] + c_ * 16);                               \
    }                                                                        \
    _Pragma("unroll")                                                        \
    for (int i_ = 0; i_ < 4; ++i_) {                                         \
      const int c_ = tid + i_ * 256;                                         \
      GLOAD_LDS16(symT + (size_t)(n0 + (c_ >> 3)) * 512 + kc_ + ((c_ & 7) << 3), \
                  (char*)Bbuf[buf] + c_ * 16);                               \
    }                                                                        \
  }

  STAGE(0, 0);
  asm volatile("s_waitcnt vmcnt(0)" ::: "memory");
  __builtin_amdgcn_s_barrier();
  __builtin_amdgcn_sched_barrier(0);

  for (int t = 0; t < 8; ++t) {
    if (t < 7) STAGE(t + 1, (t + 1) & 1);
    const char* ab = (const char*)Abuf[t & 1];
    const char* bbp = (const char*)Bbuf[t & 1];
#pragma unroll
    for (int ks = 0; ks < 2; ++ks) {
      const int col = ks * 32 + g * 8;
      short8_t af[4], bfr[4];
#pragma unroll
      for (int mr = 0; mr < 4; ++mr)
        af[mr] = *(const short8_t*)(ab + ((wr * 64 + mr * 16 + ml) * 64 + col) * 2);
#pragma unroll
      for (int nr = 0; nr < 4; ++nr)
        bfr[nr] = *(const short8_t*)(bbp + ((wc * 64 + nr * 16 + ml) * 64 + col) * 2);
#pragma unroll
      for (int mr = 0; mr < 4; ++mr)
#pragma unroll
        for (int nr = 0; nr < 4; ++nr)
          acc[mr][nr] = MFMA16(af[mr], bfr[nr], acc[mr][nr]);
    }
    // drain prefetch loads (incl. global_load_lds LDS-writes), then barrier;
    // sched_barrier pins next iteration's ds_reads below the barrier.
    asm volatile("s_waitcnt vmcnt(0)" ::: "memory");
    __builtin_amdgcn_s_barrier();
    __builtin_amdgcn_sched_barrier(0);
  }
#undef STAGE

#pragma unroll
  for (int mr = 0; mr < 4; ++mr)
#pragma unroll
    for (int i = 0; i < 4; ++i) {
      const size_t r = m0 + wr * 64 + mr * 16 + g * 4 + i;
      const float inv = rowinv[r];
#pragma unroll
      for (int nr = 0; nr < 4; ++nr)
        out[r * 1024 + n0 + wc * 64 + nr * 16 + ml] = acc[mr][nr][i] * inv;
    }
}

extern "C" void kernel_launch(void* const* d_in, const int* in_sizes, int n_in,
                              void* d_out, int out_size, void* d_ws,
                              size_t ws_size, hipStream_t stream) {
  const float* inp = (const float*)d_in[0];      // [8,4096,1024]
  const float* Wq = (const float*)d_in[1];       // [1024,1024]
  const float* binding = (const float*)d_in[2];  // [512,1024]
  const float* symbols = (const float*)d_in[3];  // [512,1024]
  float* out = (float*)d_out;                    // [8,4096,1024]

  short* MT = (short*)d_ws;            // [512][1024] bf16 (1/32 scale folded)
  short* symT = MT + 512 * 1024;       // [1024][512] bf16
  short* P = symT + 1024 * 512;        // [32768][512] bf16 unnormalized exp
  float* rowinv = (float*)(P + (size_t)32768 * 512);  // [32768] fp32

  mt_kernel<<<dim3(8, 8), 256, 0, stream>>>(Wq, binding, MT);
  tr_kernel<<<dim3(16, 8), 256, 0, stream>>>(symbols, symT);
  score_kernel<<<512, 512, 0, stream>>>(inp, MT, P, rowinv);
  pv_kernel<<<2048, 256, 0, stream>>>(P, symT, rowinv, out);
}

// Round 5
// 180.388 us; speedup vs baseline: 1.2863x; 1.1858x over previous
//
#include <hip/hip_runtime.h>

typedef __attribute__((ext_vector_type(8))) short short8_t;
typedef __attribute__((ext_vector_type(4))) short short4_t;
typedef __attribute__((ext_vector_type(4))) float float4_t;

#define MFMA16(a, b, c) __builtin_amdgcn_mfma_f32_16x16x32_bf16((a), (b), (c), 0, 0, 0)
#define GLOAD_LDS16(g, l)                                                   \
  __builtin_amdgcn_global_load_lds(                                         \
      (const __attribute__((address_space(1))) void*)(g),                   \
      (__attribute__((address_space(3))) void*)(l), 16, 0, 0)

// fp32 -> bf16 round-to-nearest-even (finite inputs only)
static __device__ __forceinline__ unsigned short f2b(float f) {
  unsigned int x = __builtin_bit_cast(unsigned int, f);
  x = (x + 0x7fffu + ((x >> 16) & 1u)) >> 16;
  return (unsigned short)x;
}

// ---------------------------------------------------------------------------
// Kernel 1: MT[j][d] = (1/32) * sum_k binding[j][k] * Wq[d][k]   (bf16 out)
// ---------------------------------------------------------------------------
__global__ __launch_bounds__(256, 2) void mt_kernel(
    const float* __restrict__ Wq, const float* __restrict__ binding,
    short* __restrict__ MT) {
  __shared__ short bl[64 * 64];
  __shared__ short wl[128 * 64];
  const int tid = threadIdx.x;
  const int wid = tid >> 6;
  const int lane = tid & 63;
  const int ml = lane & 15;
  const int g = lane >> 4;
  const int klane = g * 8;
  const int j0 = blockIdx.x * 64;
  const int d0 = blockIdx.y * 128;

  float4_t acc[4][2];
#pragma unroll
  for (int a = 0; a < 4; ++a)
#pragma unroll
    for (int b = 0; b < 2; ++b) acc[a][b] = (float4_t)(0.0f);

  const int sr = tid >> 3;
  const int sc = (tid & 7) << 3;

  for (int kc = 0; kc < 1024; kc += 64) {
#pragma unroll
    for (int rr = sr; rr < 64; rr += 32) {
      const float* s = binding + (size_t)(j0 + rr) * 1024 + kc + sc;
      float4 f0 = *(const float4*)s;
      float4 f1 = *(const float4*)(s + 4);
      short8_t v;
      v[0] = (short)f2b(f0.x); v[1] = (short)f2b(f0.y);
      v[2] = (short)f2b(f0.z); v[3] = (short)f2b(f0.w);
      v[4] = (short)f2b(f1.x); v[5] = (short)f2b(f1.y);
      v[6] = (short)f2b(f1.z); v[7] = (short)f2b(f1.w);
      *(short8_t*)((char*)bl + ((((rr * 64 + sc) * 2) ^ ((rr & 7) << 4)))) = v;
    }
#pragma unroll
    for (int rr = sr; rr < 128; rr += 32) {
      const float* s = Wq + (size_t)(d0 + rr) * 1024 + kc + sc;
      float4 f0 = *(const float4*)s;
      float4 f1 = *(const float4*)(s + 4);
      short8_t v;
      v[0] = (short)f2b(f0.x); v[1] = (short)f2b(f0.y);
      v[2] = (short)f2b(f0.z); v[3] = (short)f2b(f0.w);
      v[4] = (short)f2b(f1.x); v[5] = (short)f2b(f1.y);
      v[6] = (short)f2b(f1.z); v[7] = (short)f2b(f1.w);
      *(short8_t*)((char*)wl + ((((rr * 64 + sc) * 2) ^ ((rr & 7) << 4)))) = v;
    }
    __syncthreads();
#pragma unroll
    for (int ks = 0; ks < 2; ++ks) {
      const int col = ks * 32 + klane;
      short8_t af[4], bfr[2];
#pragma unroll
      for (int mr = 0; mr < 4; ++mr) {
        int row = mr * 16 + ml;
        af[mr] = *(const short8_t*)((const char*)bl +
                                    (((row * 64 + col) * 2) ^ ((row & 7) << 4)));
      }
#pragma unroll
      for (int nr = 0; nr < 2; ++nr) {
        int row = wid * 32 + nr * 16 + ml;
        bfr[nr] = *(const short8_t*)((const char*)wl +
                                     (((row * 64 + col) * 2) ^ ((row & 7) << 4)));
      }
#pragma unroll
      for (int mr = 0; mr < 4; ++mr)
#pragma unroll
        for (int nr = 0; nr < 2; ++nr)
          acc[mr][nr] = MFMA16(af[mr], bfr[nr], acc[mr][nr]);
    }
    __syncthreads();
  }
#pragma unroll
  for (int mr = 0; mr < 4; ++mr)
#pragma unroll
    for (int nr = 0; nr < 2; ++nr)
#pragma unroll
      for (int i = 0; i < 4; ++i) {
        int j = j0 + mr * 16 + g * 4 + i;
        int d = d0 + wid * 32 + nr * 16 + ml;
        MT[(size_t)j * 1024 + d] = (short)f2b(acc[mr][nr][i] * 0.03125f);
      }
}

// ---------------------------------------------------------------------------
// Kernel 2: symT[k][j] = bf16(symbols[j][k])  (transpose 512x1024 -> 1024x512)
// ---------------------------------------------------------------------------
__global__ __launch_bounds__(256) void tr_kernel(const float* __restrict__ sym,
                                                 short* __restrict__ symT) {
  __shared__ short t[64][65];
  const int tid = threadIdx.x;
  const int k0 = blockIdx.x * 64;
  const int j0 = blockIdx.y * 64;
  const int sr = tid >> 3;
  const int sc = (tid & 7) << 3;
#pragma unroll
  for (int rr = sr; rr < 64; rr += 32) {
    const float* s = sym + (size_t)(j0 + rr) * 1024 + k0 + sc;
    float4 f0 = *(const float4*)s;
    float4 f1 = *(const float4*)(s + 4);
    t[rr][sc + 0] = (short)f2b(f0.x); t[rr][sc + 1] = (short)f2b(f0.y);
    t[rr][sc + 2] = (short)f2b(f0.z); t[rr][sc + 3] = (short)f2b(f0.w);
    t[rr][sc + 4] = (short)f2b(f1.x); t[rr][sc + 5] = (short)f2b(f1.y);
    t[rr][sc + 6] = (short)f2b(f1.z); t[rr][sc + 7] = (short)f2b(f1.w);
  }
  __syncthreads();
  const int kk = tid >> 4;
  const int jj = (tid & 15) << 2;
#pragma unroll
  for (int k = kk; k < 64; k += 16) {
    short* dst = symT + (size_t)(k0 + k) * 512 + j0 + jj;
    dst[0] = t[jj + 0][k];
    dst[1] = t[jj + 1][k];
    dst[2] = t[jj + 2][k];
    dst[3] = t[jj + 3][k];
  }
}

// ---------------------------------------------------------------------------
// Kernel 3: score. logitsT = MT @ bf16(inp)^T (swapped operands), row max,
// P = bf16(exp(x - m)) UNNORMALIZED -> global ws, rowinv = 1/rowsum (fp32).
// grid 512 (64-row tiles), block 512 (8 waves), wave owns a 64-j strip.
// MT fragment loads issued ABOVE the barrier (race-free: global, not LDS) so
// their L2 latency hides under barrier+ds_reads; sched_barrier(0) pins only
// the Abuf ds_reads below the barrier (the R2/R3 race fix, kept).
// ---------------------------------------------------------------------------
__global__ __launch_bounds__(512, 2) void score_kernel(
    const float* __restrict__ inp, const short* __restrict__ MT,
    short* __restrict__ P, float* __restrict__ rowinv) {
  __shared__ short Abuf[2][64 * 64];
  __shared__ float redmax[8 * 64];
  __shared__ float redsum[8 * 64];

  const int tid = threadIdx.x;
  const int wid = tid >> 6;
  const int lane = tid & 63;
  const int ml = lane & 15;
  const int g = lane >> 4;
  const size_t row0 = (size_t)blockIdx.x * 64;

  float4_t acc[4][4];  // acc[jm][rm]: D[j][r], j = wid*64+jm*16+g*4+i, r = rm*16+ml
#pragma unroll
  for (int a = 0; a < 4; ++a)
#pragma unroll
    for (int b = 0; b < 4; ++b) acc[a][b] = (float4_t)(0.0f);

  const int sr = tid >> 3;        // 0..63 row within tile
  const int sc = (tid & 7) << 3;  // col chunk
  const float* srcbase = inp + (row0 + sr) * 1024 + sc;
  // per-wave MT base: row (wid*64 + ml), col offset g*8
  const short* mtbase = MT + (size_t)(wid * 64 + ml) * 1024 + g * 8;

  float4 f0 = *(const float4*)(srcbase);
  float4 f1 = *(const float4*)(srcbase + 4);

  for (int kt = 0; kt < 16; ++kt) {
    // convert prefetched fp32 -> bf16, write to current LDS buffer (swizzled)
    short8_t v;
    v[0] = (short)f2b(f0.x); v[1] = (short)f2b(f0.y);
    v[2] = (short)f2b(f0.z); v[3] = (short)f2b(f0.w);
    v[4] = (short)f2b(f1.x); v[5] = (short)f2b(f1.y);
    v[6] = (short)f2b(f1.z); v[7] = (short)f2b(f1.w);
    *(short8_t*)((char*)Abuf[kt & 1] + (((sr * 64 + sc) * 2) ^ ((sr & 7) << 4))) = v;

    // current kt's MT fragments — global loads, issued BEFORE the barrier so
    // L2 latency overlaps the barrier + ds_reads. Issued before inp prefetch
    // so the auto-waitcnt before first MFMA is vmcnt(2) (inp stays in flight).
    const short* mtb = mtbase + kt * 64;
    short8_t af0[4], af1[4];
#pragma unroll
    for (int jm = 0; jm < 4; ++jm) {
      af0[jm] = *(const short8_t*)(mtb + jm * 16 * 1024);
      af1[jm] = *(const short8_t*)(mtb + jm * 16 * 1024 + 32);
    }

    // issue next tile's inp loads (consumed at next iteration's convert)
    if (kt < 15) {
      const float* s2 = srcbase + (kt + 1) * 64;
      f0 = *(const float4*)s2;
      f1 = *(const float4*)(s2 + 4);
    }

    // drain own LDS write; global loads stay in flight
    asm volatile("s_waitcnt lgkmcnt(0)" ::: "memory");
    __builtin_amdgcn_s_barrier();
    // pin: the Abuf ds_reads below may not hoist above the barrier
    __builtin_amdgcn_sched_barrier(0);

    const char* bb = (const char*)Abuf[kt & 1];
#pragma unroll
    for (int ks = 0; ks < 2; ++ks) {
      const int col = ks * 32 + g * 8;
      short8_t bfr[4];
#pragma unroll
      for (int rm = 0; rm < 4; ++rm) {
        int row = rm * 16 + ml;
        bfr[rm] = *(const short8_t*)(bb + (((row * 64 + col) * 2) ^ ((row & 7) << 4)));
      }
#pragma unroll
      for (int jm = 0; jm < 4; ++jm)
#pragma unroll
        for (int rm = 0; rm < 4; ++rm)
          acc[jm][rm] = MFMA16(ks == 0 ? af0[jm] : af1[jm], bfr[rm], acc[jm][rm]);
    }
    // no trailing barrier: next write targets the other buffer, and the
    // kt+1 barrier (all waves' lgkm drained) orders reuse of this buffer.
  }

  // ---- row max over j (512), rows r = rm*16+ml ----
#pragma unroll
  for (int rm = 0; rm < 4; ++rm) {
    float mx = -1e30f;
#pragma unroll
    for (int jm = 0; jm < 4; ++jm)
#pragma unroll
      for (int i = 0; i < 4; ++i) mx = fmaxf(mx, acc[jm][rm][i]);
    mx = fmaxf(mx, __shfl_xor(mx, 16));
    mx = fmaxf(mx, __shfl_xor(mx, 32));
    if (g == 0) redmax[wid * 64 + rm * 16 + ml] = mx;
  }
  __syncthreads();

  // ---- exp(x-m), write unnormalized bf16 P, reduce row sums ----
#pragma unroll
  for (int rm = 0; rm < 4; ++rm) {
    const int row = rm * 16 + ml;
    float m = redmax[row];
#pragma unroll
    for (int w = 1; w < 8; ++w) m = fmaxf(m, redmax[w * 64 + row]);
    float s = 0.0f;
#pragma unroll
    for (int jm = 0; jm < 4; ++jm) {
      short4_t pv;
#pragma unroll
      for (int i = 0; i < 4; ++i) {
        float p = __expf(acc[jm][rm][i] - m);
        s += p;
        pv[i] = (short)f2b(p);
      }
      *(short4_t*)(P + ((row0 + row) << 9) + wid * 64 + jm * 16 + g * 4) = pv;
    }
    s += __shfl_xor(s, 16);
    s += __shfl_xor(s, 32);
    if (g == 0) redsum[wid * 64 + row] = s;
  }
  __syncthreads();

  // ---- wave 0 writes 1/rowsum ----
  if (wid == 0 && g == 0) {
#pragma unroll
    for (int rm = 0; rm < 4; ++rm) {
      const int row = rm * 16 + ml;
      float t = 0.0f;
#pragma unroll
      for (int w = 0; w < 8; ++w) t += redsum[w * 64 + row];
      rowinv[row0 + row] = 1.0f / t;
    }
  }
}

// ---------------------------------------------------------------------------
// Kernel 4: out[r][d] = rowinv[r] * sum_j P[r][j] * symT[d][j].  128x128 tile,
// BK=64, 256 threads (4 waves, 2x2), global_load_lds double-buffered prefetch.
// LDS XOR-swizzle via INVERSE-PERMUTED GLOBAL SOURCE (rule #21): gload_lds
// dest stays linear; source col-chunk ^= row&7 (within-128B permutation, so
// coalescing is preserved); ds_reads use the swizzled address. Kills the
// 16-way bank conflict of linear [128][64] bf16 tiles.
// ---------------------------------------------------------------------------
__global__ __launch_bounds__(256, 2) void pv_kernel(
    const short* __restrict__ P, const short* __restrict__ symT,
    const float* __restrict__ rowinv, float* __restrict__ out) {
  __shared__ short Abuf[2][128 * 64];
  __shared__ short Bbuf[2][128 * 64];
  const int tid = threadIdx.x;
  const int lane = tid & 63;
  const int ml = lane & 15;
  const int g = lane >> 4;
  const int wid = tid >> 6;
  const int wr = wid >> 1;
  const int wc = wid & 1;

  const int b = blockIdx.x;
  const int swz = (b & 7) * 256 + (b >> 3);
  const size_t m0 = (size_t)(swz >> 3) * 128;
  const int n0 = (swz & 7) * 128;

  float4_t acc[4][4];
#pragma unroll
  for (int a = 0; a < 4; ++a)
#pragma unroll
    for (int c = 0; c < 4; ++c) acc[a][c] = (float4_t)(0.0f);

  // source col-chunk permutation: chunk ^ (row & 7)
#define STAGE(t, buf)                                                        \
  {                                                                          \
    const int kc_ = (t) * 64;                                                \
    _Pragma("unroll")                                                        \
    for (int i_ = 0; i_ < 4; ++i_) {                                         \
      const int c_ = tid + i_ * 256;                                         \
      const int r_ = c_ >> 3;                                                \
      const int ck_ = ((c_ & 7) ^ (r_ & 7)) << 3;                            \
      GLOAD_LDS16(P + (m0 + r_) * 512 + kc_ + ck_,                           \
                  (char*)Abuf[buf] + c_ * 16);                               \
    }                                                                        \
    _Pragma("unroll")                                                        \
    for (int i_ = 0; i_ < 4; ++i_) {                                         \
      const int c_ = tid + i_ * 256;                                         \
      const int r_ = c_ >> 3;                                                \
      const int ck_ = ((c_ & 7) ^ (r_ & 7)) << 3;                            \
      GLOAD_LDS16(symT + (size_t)(n0 + r_) * 512 + kc_ + ck_,                \
                  (char*)Bbuf[buf] + c_ * 16);                               \
    }                                                                        \
  }

  STAGE(0, 0);
  asm volatile("s_waitcnt vmcnt(0)" ::: "memory");
  __builtin_amdgcn_s_barrier();
  __builtin_amdgcn_sched_barrier(0);

  for (int t = 0; t < 8; ++t) {
    if (t < 7) STAGE(t + 1, (t + 1) & 1);
    const char* ab = (const char*)Abuf[t & 1];
    const char* bbp = (const char*)Bbuf[t & 1];
#pragma unroll
    for (int ks = 0; ks < 2; ++ks) {
      const int col = ks * 32 + g * 8;
      short8_t af[4], bfr[4];
#pragma unroll
      for (int mr = 0; mr < 4; ++mr) {
        const int row = wr * 64 + mr * 16 + ml;
        af[mr] = *(const short8_t*)(ab + (((row * 64 + col) * 2) ^ ((row & 7) << 4)));
      }
#pragma unroll
      for (int nr = 0; nr < 4; ++nr) {
        const int row = wc * 64 + nr * 16 + ml;
        bfr[nr] = *(const short8_t*)(bbp + (((row * 64 + col) * 2) ^ ((row & 7) << 4)));
      }
#pragma unroll
      for (int mr = 0; mr < 4; ++mr)
#pragma unroll
        for (int nr = 0; nr < 4; ++nr)
          acc[mr][nr] = MFMA16(af[mr], bfr[nr], acc[mr][nr]);
    }
    // drain prefetch loads (incl. global_load_lds LDS-writes), then barrier;
    // sched_barrier pins next iteration's ds_reads below the barrier.
    asm volatile("s_waitcnt vmcnt(0)" ::: "memory");
    __builtin_amdgcn_s_barrier();
    __builtin_amdgcn_sched_barrier(0);
  }
#undef STAGE

#pragma unroll
  for (int mr = 0; mr < 4; ++mr)
#pragma unroll
    for (int i = 0; i < 4; ++i) {
      const size_t r = m0 + wr * 64 + mr * 16 + g * 4 + i;
      const float inv = rowinv[r];
#pragma unroll
      for (int nr = 0; nr < 4; ++nr)
        out[r * 1024 + n0 + wc * 64 + nr * 16 + ml] = acc[mr][nr][i] * inv;
    }
}

extern "C" void kernel_launch(void* const* d_in, const int* in_sizes, int n_in,
                              void* d_out, int out_size, void* d_ws,
                              size_t ws_size, hipStream_t stream) {
  const float* inp = (const float*)d_in[0];      // [8,4096,1024]
  const float* Wq = (const float*)d_in[1];       // [1024,1024]
  const float* binding = (const float*)d_in[2];  // [512,1024]
  const float* symbols = (const float*)d_in[3];  // [512,1024]
  float* out = (float*)d_out;                    // [8,4096,1024]

  short* MT = (short*)d_ws;            // [512][1024] bf16 (1/32 scale folded)
  short* symT = MT + 512 * 1024;       // [1024][512] bf16
  short* P = symT + 1024 * 512;        // [32768][512] bf16 unnormalized exp
  float* rowinv = (float*)(P + (size_t)32768 * 512);  // [32768] fp32

  mt_kernel<<<dim3(8, 8), 256, 0, stream>>>(Wq, binding, MT);
  tr_kernel<<<dim3(16, 8), 256, 0, stream>>>(symbols, symT);
  score_kernel<<<512, 512, 0, stream>>>(inp, MT, P, rowinv);
  pv_kernel<<<2048, 256, 0, stream>>>(P, symT, rowinv, out);
}